// Round 1
// 3585.882 us; speedup vs baseline: 1.4046x; 1.4046x over previous
//
#include <hip/hip_runtime.h>
#include <hip/hip_bf16.h>
#include <math.h>

typedef __bf16 bf16x8 __attribute__((ext_vector_type(8)));
typedef float f32x4 __attribute__((ext_vector_type(4)));

#define TOK 4096   // B*S
#define HDIM 4096
#define IDIM 11008

// ---------------------------------------------------------------------------
// 64x64 Kron transform + fake quant:  T = L^T * (X op diag) * R, per row.
// mulDiag=1: X = src*diag (activations); mulDiag=0: X = src/diag (weights,
// using L^T/R in place of inv(L)/inv(R)^T since L,R are orthonormal).
// Output: quantized integer values stored exactly as bf16, per-row scale.
// ---------------------------------------------------------------------------
__global__ __launch_bounds__(256) void t64_kernel(
    const float* __restrict__ src, const float* __restrict__ Lm,
    const float* __restrict__ Rm, const float* __restrict__ diag,
    __hip_bfloat16* __restrict__ outq, float* __restrict__ scales,
    int mulDiag, float qmax, float qlo, float qhi)
{
    __shared__ float X[64 * 68];   // stride 68: 16B-aligned rows, bank-spread
    __shared__ float M1[64 * 68];
    __shared__ float LR[64 * 68];
    const int tid = threadIdx.x;
    const int row = blockIdx.x;
    const float* srow = src + (size_t)row * 4096;

    for (int idx = tid; idx < 4096; idx += 256) {
        float d = diag[idx];
        float v = srow[idx];
        v = mulDiag ? v * d : v / d;
        X[(idx >> 6) * 68 + (idx & 63)] = v;
        LR[(idx >> 6) * 68 + (idx & 63)] = Lm[idx];
    }
    __syncthreads();

    const int p0 = (tid >> 4) << 2;
    const int j0 = (tid & 15) << 2;

    // M1 = L^T X : M1[p][j] = sum_i L[i][p] * X[i][j]
    float acc[4][4] = {};
    for (int i = 0; i < 64; ++i) {
        float a[4];
#pragma unroll
        for (int ii = 0; ii < 4; ++ii) a[ii] = LR[i * 68 + p0 + ii];
        float4 b = *(const float4*)&X[i * 68 + j0];
        float bv[4] = {b.x, b.y, b.z, b.w};
#pragma unroll
        for (int ii = 0; ii < 4; ++ii)
#pragma unroll
            for (int jj = 0; jj < 4; ++jj) acc[ii][jj] += a[ii] * bv[jj];
    }
#pragma unroll
    for (int ii = 0; ii < 4; ++ii)
        *(float4*)&M1[(p0 + ii) * 68 + j0] =
            make_float4(acc[ii][0], acc[ii][1], acc[ii][2], acc[ii][3]);
    __syncthreads();

    for (int idx = tid; idx < 4096; idx += 256)
        LR[(idx >> 6) * 68 + (idx & 63)] = Rm[idx];
    __syncthreads();

    // T = M1 R : T[p][q] = sum_j M1[p][j] * R[j][q]
    float acc2[4][4] = {};
    for (int j = 0; j < 64; ++j) {
        float a[4];
#pragma unroll
        for (int ii = 0; ii < 4; ++ii) a[ii] = M1[(p0 + ii) * 68 + j];
        float4 b = *(const float4*)&LR[j * 68 + j0];
        float bv[4] = {b.x, b.y, b.z, b.w};
#pragma unroll
        for (int ii = 0; ii < 4; ++ii)
#pragma unroll
            for (int jj = 0; jj < 4; ++jj) acc2[ii][jj] += a[ii] * bv[jj];
    }

    // row absmax reduction (reuse X, which is dead)
    float lm = 0.f;
#pragma unroll
    for (int ii = 0; ii < 4; ++ii)
#pragma unroll
        for (int jj = 0; jj < 4; ++jj) lm = fmaxf(lm, fabsf(acc2[ii][jj]));
    X[tid] = lm;
    __syncthreads();
    for (int s = 128; s > 0; s >>= 1) {
        if (tid < s) X[tid] = fmaxf(X[tid], X[tid + s]);
        __syncthreads();
    }
    const float sc = fmaxf(X[0] / qmax, 1e-8f);

#pragma unroll
    for (int ii = 0; ii < 4; ++ii)
#pragma unroll
        for (int jj = 0; jj < 4; ++jj) {
            float q = rintf(acc2[ii][jj] / sc);
            q = fminf(fmaxf(q, qlo), qhi);
            outq[(size_t)row * 4096 + (p0 + ii) * 64 + (j0 + jj)] =
                __float2bfloat16(q);
        }
    if (tid == 0) scales[row] = sc;
}

// ---------------------------------------------------------------------------
// 86x128 Kron transform + fake quant (dn branch). Dynamic LDS 158400 B.
// src may be f32 (w_down) or bf16 (h, in-place).
// ---------------------------------------------------------------------------
__global__ __launch_bounds__(512) void tdn_kernel(
    const void* __restrict__ src, int srcIsBf16,
    const float* __restrict__ Lm, const float* __restrict__ Rm,
    const float* __restrict__ diag,
    __hip_bfloat16* __restrict__ outq, float* __restrict__ scales,
    int mulDiag, float qmax, float qlo, float qhi)
{
    extern __shared__ float dsm[];
    float* X  = dsm;              // 86*132 = 11352
    float* M1 = dsm + 11352;      // 86*132
    float* LR = dsm + 22704;      // up to 128*132 = 16896
    __shared__ float red[512];

    const int tid = threadIdx.x;
    const int row = blockIdx.x;

    for (int idx = tid; idx < IDIM; idx += 512) {
        float v = srcIsBf16
            ? __bfloat162float(((const __hip_bfloat16*)src)[(size_t)row * IDIM + idx])
            : ((const float*)src)[(size_t)row * IDIM + idx];
        float d = diag[idx];
        v = mulDiag ? v * d : v / d;
        X[(idx >> 7) * 132 + (idx & 127)] = v;
    }
    for (int idx = tid; idx < 86 * 86; idx += 512) {
        int r = idx / 86, c = idx - r * 86;
        LR[r * 88 + c] = Lm[idx];     // L with stride 88
    }
    __syncthreads();

    // M1[86][128] = L^T X ; 2x4 output tiles, 43*32 = 1376 tiles
    for (int tt = tid; tt < 1376; tt += 512) {
        const int pp = (tt >> 5) * 2;
        const int jj0 = (tt & 31) * 4;
        float acc[2][4] = {};
        for (int i = 0; i < 86; ++i) {
            float a0 = LR[i * 88 + pp];
            float a1 = LR[i * 88 + pp + 1];
            float4 b = *(const float4*)&X[i * 132 + jj0];
            acc[0][0] += a0 * b.x; acc[0][1] += a0 * b.y;
            acc[0][2] += a0 * b.z; acc[0][3] += a0 * b.w;
            acc[1][0] += a1 * b.x; acc[1][1] += a1 * b.y;
            acc[1][2] += a1 * b.z; acc[1][3] += a1 * b.w;
        }
        *(float4*)&M1[pp * 132 + jj0] =
            make_float4(acc[0][0], acc[0][1], acc[0][2], acc[0][3]);
        *(float4*)&M1[(pp + 1) * 132 + jj0] =
            make_float4(acc[1][0], acc[1][1], acc[1][2], acc[1][3]);
    }
    __syncthreads();

    for (int idx = tid; idx < 128 * 128; idx += 512) {
        int r = idx >> 7, c = idx & 127;
        LR[r * 132 + c] = Rm[idx];    // R with stride 132
    }
    __syncthreads();

    // T[86][128] = M1 R, into X (dead); track absmax
    float lm = 0.f;
    for (int tt = tid; tt < 1376; tt += 512) {
        const int pp = (tt >> 5) * 2;
        const int q0 = (tt & 31) * 4;
        float acc[2][4] = {};
        for (int j = 0; j < 128; ++j) {
            float a0 = M1[pp * 132 + j];
            float a1 = M1[(pp + 1) * 132 + j];
            float4 b = *(const float4*)&LR[j * 132 + q0];
            acc[0][0] += a0 * b.x; acc[0][1] += a0 * b.y;
            acc[0][2] += a0 * b.z; acc[0][3] += a0 * b.w;
            acc[1][0] += a1 * b.x; acc[1][1] += a1 * b.y;
            acc[1][2] += a1 * b.z; acc[1][3] += a1 * b.w;
        }
        *(float4*)&X[pp * 132 + q0] =
            make_float4(acc[0][0], acc[0][1], acc[0][2], acc[0][3]);
        *(float4*)&X[(pp + 1) * 132 + q0] =
            make_float4(acc[1][0], acc[1][1], acc[1][2], acc[1][3]);
#pragma unroll
        for (int ii = 0; ii < 2; ++ii)
#pragma unroll
            for (int qq = 0; qq < 4; ++qq) lm = fmaxf(lm, fabsf(acc[ii][qq]));
    }
    red[tid] = lm;
    __syncthreads();
    for (int s = 256; s > 0; s >>= 1) {
        if (tid < s) red[tid] = fmaxf(red[tid], red[tid + s]);
        __syncthreads();
    }
    const float sc = fmaxf(red[0] / qmax, 1e-8f);

    for (int idx = tid; idx < IDIM; idx += 512) {
        float v = X[(idx >> 7) * 132 + (idx & 127)];
        float q = rintf(v / sc);
        q = fminf(fmaxf(q, qlo), qhi);
        outq[(size_t)row * IDIM + idx] = __float2bfloat16(q);
    }
    if (tid == 0) scales[row] = sc;
}

// ---------------------------------------------------------------------------
// async global->LDS, 16B per lane. LDS dest is wave-uniform base + lane*16.
// ---------------------------------------------------------------------------
__device__ __forceinline__ void gload16(const __hip_bfloat16* gsrc,
                                        __hip_bfloat16* ldst)
{
    __builtin_amdgcn_global_load_lds(
        (const __attribute__((address_space(1))) unsigned int*)gsrc,
        (__attribute__((address_space(3))) unsigned int*)ldst, 16, 0, 0);
}

// ---------------------------------------------------------------------------
// Tiled bf16 MFMA GEMM, C = A * B^T (both row-major-K). m97-structure:
// 128x128 tile, BK=64, 4 waves (2x2), 4x4 16x16 frags per wave,
// global_load_lds width-16 staging (linear LDS, no VALU round-trip).
// Integer-valued bf16 inputs -> exact integer accumulation in f32.
// DUAL: two B matrices (up/gate) + SwiGLU epilogue -> bf16 h.
// SINGLE: one B + dequant epilogue -> f32 out.
// ---------------------------------------------------------------------------
template <bool DUAL>
__global__ __launch_bounds__(256, 2) void gemm_kernel(
    const __hip_bfloat16* __restrict__ A,
    const __hip_bfloat16* __restrict__ B0,
    const __hip_bfloat16* __restrict__ B1,
    const float* __restrict__ sA,
    const float* __restrict__ sB0,
    const float* __restrict__ sB1,
    int K,
    __hip_bfloat16* __restrict__ outH,
    float* __restrict__ outF,
    int outLd)
{
    constexpr int NT = DUAL ? 3 : 2;
    constexpr int TSZ = 128 * 64;                    // elems per staged tile
    __shared__ __align__(16) __hip_bfloat16 smem[NT * TSZ];

    const int tid = threadIdx.x;
    const int lane = tid & 63;
    const int lane15 = lane & 15;
    const int quad = lane >> 4;
    const int wave = tid >> 6;
    const int wr = wave >> 1;        // wave row (0..1) -> 64-row half
    const int wc = wave & 1;         // wave col (0..1) -> 64-col half
    const int n0 = blockIdx.x * 128;
    const int m0 = blockIdx.y * 128;

    // staging geometry: one gload16 call = 64 lanes * 16B = 8 rows of 64 elems
    const int srow = lane >> 3;          // row within 8-row chunk
    const int scol = (lane & 7) * 8;     // elem col within 64-elem row

    f32x4 acc0[4][4] = {};
    f32x4 acc1[4][4] = {};

    const __hip_bfloat16* gA  = A + (size_t)m0 * K;
    const __hip_bfloat16* gB0 = B0 + (size_t)n0 * K;
    const __hip_bfloat16* gB1 = DUAL ? (B1 + (size_t)n0 * K) : nullptr;

    for (int kk = 0; kk < K; kk += 64) {
        // stage A | B0 | (B1): per wave 4 chunks of 8 rows per tile
#pragma unroll
        for (int c = 0; c < 4; ++c) {
            const int r0 = wave * 32 + c * 8;
            gload16(gA + (size_t)(r0 + srow) * K + kk + scol,
                    smem + r0 * 64);
            gload16(gB0 + (size_t)(r0 + srow) * K + kk + scol,
                    smem + TSZ + r0 * 64);
            if constexpr (DUAL)
                gload16(gB1 + (size_t)(r0 + srow) * K + kk + scol,
                        smem + 2 * TSZ + r0 * 64);
        }
        __syncthreads();   // compiler emits vmcnt(0) drain here (m97 structure)

#pragma unroll
        for (int ks = 0; ks < 2; ++ks) {
            const int kb = ks * 32 + quad * 8;
            bf16x8 af[4];
#pragma unroll
            for (int m = 0; m < 4; ++m)
                af[m] = *(const bf16x8*)(smem +
                         (wr * 64 + m * 16 + lane15) * 64 + kb);
#pragma unroll
            for (int c = 0; c < 4; ++c) {
                bf16x8 b0 = *(const bf16x8*)(smem + TSZ +
                             (wc * 64 + c * 16 + lane15) * 64 + kb);
#pragma unroll
                for (int m = 0; m < 4; ++m)
                    acc0[m][c] = __builtin_amdgcn_mfma_f32_16x16x32_bf16(
                        af[m], b0, acc0[m][c], 0, 0, 0);
                if constexpr (DUAL) {
                    bf16x8 b1 = *(const bf16x8*)(smem + 2 * TSZ +
                                 (wc * 64 + c * 16 + lane15) * 64 + kb);
#pragma unroll
                    for (int m = 0; m < 4; ++m)
                        acc1[m][c] = __builtin_amdgcn_mfma_f32_16x16x32_bf16(
                            af[m], b1, acc1[m][c], 0, 0, 0);
                }
            }
        }
        __syncthreads();
    }

    // Epilogue. Frag D[row=quad*4+r][col=lane15].
#pragma unroll
    for (int m = 0; m < 4; ++m) {
        const int r0 = m0 + wr * 64 + m * 16 + quad * 4;
        float sa[4];
#pragma unroll
        for (int r = 0; r < 4; ++r) sa[r] = sA[r0 + r];
#pragma unroll
        for (int c = 0; c < 4; ++c) {
            const int col = n0 + wc * 64 + c * 16 + lane15;
            if constexpr (DUAL) {
                const float s0 = sB0[col], s1 = sB1[col];
#pragma unroll
                for (int r = 0; r < 4; ++r) {
                    float up = acc0[m][c][r] * (sa[r] * s0);
                    float gt = acc1[m][c][r] * (sa[r] * s1);
                    float hv = up * (gt / (1.f + __expf(-gt)));   // silu(g)*up
                    outH[(size_t)(r0 + r) * outLd + col] = __float2bfloat16(hv);
                }
            } else {
                const float s0 = sB0[col];
#pragma unroll
                for (int r = 0; r < 4; ++r)
                    outF[(size_t)(r0 + r) * outLd + col] =
                        acc0[m][c][r] * (sa[r] * s0);
            }
        }
    }
}

// ---------------------------------------------------------------------------
extern "C" void kernel_launch(void* const* d_in, const int* in_sizes, int n_in,
                              void* d_out, int out_size, void* d_ws, size_t ws_size,
                              hipStream_t stream)
{
    const float* x       = (const float*)d_in[0];
    const float* w_up    = (const float*)d_in[1];
    const float* w_gate  = (const float*)d_in[2];
    const float* w_down  = (const float*)d_in[3];
    const float* up_L    = (const float*)d_in[4];
    const float* up_R    = (const float*)d_in[5];
    const float* up_diag = (const float*)d_in[6];
    const float* dn_L    = (const float*)d_in[7];
    const float* dn_R    = (const float*)d_in[8];
    const float* dn_diag = (const float*)d_in[9];
    float* out = (float*)d_out;

    char* w = (char*)d_ws;
    size_t off = 0;
    auto take = [&](size_t b) { char* p = w + off; off += (b + 255) & ~(size_t)255; return p; };
    __hip_bfloat16* wuq = (__hip_bfloat16*)take((size_t)IDIM * HDIM * 2);
    __hip_bfloat16* wgq = (__hip_bfloat16*)take((size_t)IDIM * HDIM * 2);
    __hip_bfloat16* wdq = (__hip_bfloat16*)take((size_t)HDIM * IDIM * 2);
    __hip_bfloat16* xq  = (__hip_bfloat16*)take((size_t)TOK * HDIM * 2);
    __hip_bfloat16* hq  = (__hip_bfloat16*)take((size_t)TOK * IDIM * 2);
    float* sx = (float*)take(TOK * 4);
    float* su = (float*)take(IDIM * 4);
    float* sg = (float*)take(IDIM * 4);
    float* sh = (float*)take(TOK * 4);
    float* sd = (float*)take(HDIM * 4);
    (void)in_sizes; (void)n_in; (void)out_size; (void)ws_size;

    const size_t tdn_lds = (size_t)(11352 + 11352 + 16896) * sizeof(float); // 158400
    hipFuncSetAttribute(reinterpret_cast<const void*>(&tdn_kernel),
                        hipFuncAttributeMaxDynamicSharedMemorySize, (int)tdn_lds);

    // 1) activation + weight transforms/quant
    t64_kernel<<<TOK,  256, 0, stream>>>(x,      up_L, up_R, up_diag, xq,  sx, 1, 127.f, -128.f, 127.f);
    t64_kernel<<<IDIM, 256, 0, stream>>>(w_up,   up_L, up_R, up_diag, wuq, su, 0, 7.f,   -8.f,   7.f);
    t64_kernel<<<IDIM, 256, 0, stream>>>(w_gate, up_L, up_R, up_diag, wgq, sg, 0, 7.f,   -8.f,   7.f);
    tdn_kernel<<<HDIM, 512, tdn_lds, stream>>>(w_down, 0, dn_L, dn_R, dn_diag, wdq, sd, 0, 7.f, -8.f, 7.f);

    // 2) fused up/gate GEMM + SwiGLU -> h (bf16)  [128x128 tiles]
    gemm_kernel<true><<<dim3(IDIM / 128, TOK / 128), 256, 0, stream>>>(
        xq, wuq, wgq, sx, su, sg, HDIM, hq, nullptr, IDIM);

    // 3) dn transform + quant of h (in place)
    tdn_kernel<<<TOK, 512, tdn_lds, stream>>>(hq, 1, dn_L, dn_R, dn_diag, hq, sh, 1, 127.f, -128.f, 127.f);

    // 4) down GEMM -> f32 output  [128x128 tiles]
    gemm_kernel<false><<<dim3(HDIM / 128, TOK / 128), 256, 0, stream>>>(
        hq, wdq, nullptr, sh, sd, nullptr, IDIM, nullptr, out, HDIM);
}

// Round 2
// 3545.253 us; speedup vs baseline: 1.4207x; 1.0115x over previous
//
#include <hip/hip_runtime.h>
#include <hip/hip_bf16.h>
#include <math.h>

typedef __bf16 bf16x8 __attribute__((ext_vector_type(8)));
typedef float f32x4 __attribute__((ext_vector_type(4)));

#define TOK 4096   // B*S
#define HDIM 4096
#define IDIM 11008

__device__ __forceinline__ unsigned int bf16bits(float f)
{
    __hip_bfloat16 h = __float2bfloat16(f);
    union { __hip_bfloat16 h; unsigned short u; } cv;
    cv.h = h;
    return (unsigned int)cv.u;
}

// ---------------------------------------------------------------------------
// 64x64 Kron transform + fake quant:  T = L^T * (X op diag) * R, per row.
// All LDS accesses are float4 (b128). M1 is stored TRANSPOSED (M1T[j][p])
// so phase-2's A-operand column read is a contiguous float4 broadcast.
// ---------------------------------------------------------------------------
__global__ __launch_bounds__(256) void t64_kernel(
    const float* __restrict__ src, const float* __restrict__ Lm,
    const float* __restrict__ Rm, const float* __restrict__ diag,
    __hip_bfloat16* __restrict__ outq, float* __restrict__ scales,
    int mulDiag, float qmax, float qlo, float qhi)
{
    __shared__ float X[64 * 68];   // stride 68: 16B-aligned rows, bank-spread
    __shared__ float M1[64 * 68];  // holds M1^T: M1[j*68 + p]
    __shared__ float LR[64 * 68];
    const int tid = threadIdx.x;
    const int row = blockIdx.x;
    const float* srow = src + (size_t)row * 4096;

    for (int i4 = tid; i4 < 1024; i4 += 256) {
        const int idx = i4 * 4;
        float4 d = *(const float4*)(diag + idx);
        float4 v = *(const float4*)(srow + idx);
        float4 l = *(const float4*)(Lm + idx);
        if (mulDiag) { v.x *= d.x; v.y *= d.y; v.z *= d.z; v.w *= d.w; }
        else         { v.x /= d.x; v.y /= d.y; v.z /= d.z; v.w /= d.w; }
        const int r = idx >> 6, c = idx & 63;
        *(float4*)&X[r * 68 + c] = v;
        *(float4*)&LR[r * 68 + c] = l;
    }
    __syncthreads();

    const int p0 = (tid >> 4) << 2;
    const int j0 = (tid & 15) << 2;

    // M1[p][j] = sum_i L[i][p] * X[i][j]; store transposed M1T[j][p]
    float acc[4][4] = {};
#pragma unroll 2
    for (int i = 0; i < 64; ++i) {
        float4 a = *(const float4*)&LR[i * 68 + p0];
        float4 b = *(const float4*)&X[i * 68 + j0];
        acc[0][0] += a.x * b.x; acc[0][1] += a.x * b.y; acc[0][2] += a.x * b.z; acc[0][3] += a.x * b.w;
        acc[1][0] += a.y * b.x; acc[1][1] += a.y * b.y; acc[1][2] += a.y * b.z; acc[1][3] += a.y * b.w;
        acc[2][0] += a.z * b.x; acc[2][1] += a.z * b.y; acc[2][2] += a.z * b.z; acc[2][3] += a.z * b.w;
        acc[3][0] += a.w * b.x; acc[3][1] += a.w * b.y; acc[3][2] += a.w * b.z; acc[3][3] += a.w * b.w;
    }
#pragma unroll
    for (int jj = 0; jj < 4; ++jj)
        *(float4*)&M1[(j0 + jj) * 68 + p0] =
            make_float4(acc[0][jj], acc[1][jj], acc[2][jj], acc[3][jj]);
    __syncthreads();

    for (int i4 = tid; i4 < 1024; i4 += 256) {
        const int idx = i4 * 4;
        *(float4*)&LR[(idx >> 6) * 68 + (idx & 63)] = *(const float4*)(Rm + idx);
    }
    __syncthreads();

    // T[p][q] = sum_j M1[p][j] * R[j][q] = sum_j M1T[j][p] * R[j][q]
    float acc2[4][4] = {};
#pragma unroll 2
    for (int j = 0; j < 64; ++j) {
        float4 a = *(const float4*)&M1[j * 68 + p0];
        float4 b = *(const float4*)&LR[j * 68 + j0];
        acc2[0][0] += a.x * b.x; acc2[0][1] += a.x * b.y; acc2[0][2] += a.x * b.z; acc2[0][3] += a.x * b.w;
        acc2[1][0] += a.y * b.x; acc2[1][1] += a.y * b.y; acc2[1][2] += a.y * b.z; acc2[1][3] += a.y * b.w;
        acc2[2][0] += a.z * b.x; acc2[2][1] += a.z * b.y; acc2[2][2] += a.z * b.z; acc2[2][3] += a.z * b.w;
        acc2[3][0] += a.w * b.x; acc2[3][1] += a.w * b.y; acc2[3][2] += a.w * b.z; acc2[3][3] += a.w * b.w;
    }

    // row absmax reduction (reuse X, which is dead)
    float lm = 0.f;
#pragma unroll
    for (int ii = 0; ii < 4; ++ii)
#pragma unroll
        for (int jj = 0; jj < 4; ++jj) lm = fmaxf(lm, fabsf(acc2[ii][jj]));
    X[tid] = lm;
    __syncthreads();
    for (int s = 128; s > 0; s >>= 1) {
        if (tid < s) X[tid] = fmaxf(X[tid], X[tid + s]);
        __syncthreads();
    }
    const float sc = fmaxf(X[0] / qmax, 1e-8f);

#pragma unroll
    for (int ii = 0; ii < 4; ++ii) {
        unsigned int lo, hi;
        {
            float q0 = fminf(fmaxf(rintf(acc2[ii][0] / sc), qlo), qhi);
            float q1 = fminf(fmaxf(rintf(acc2[ii][1] / sc), qlo), qhi);
            float q2 = fminf(fmaxf(rintf(acc2[ii][2] / sc), qlo), qhi);
            float q3 = fminf(fmaxf(rintf(acc2[ii][3] / sc), qlo), qhi);
            lo = bf16bits(q0) | (bf16bits(q1) << 16);
            hi = bf16bits(q2) | (bf16bits(q3) << 16);
        }
        *(uint2*)(outq + (size_t)row * 4096 + (p0 + ii) * 64 + j0) =
            make_uint2(lo, hi);
    }
    if (tid == 0) scales[row] = sc;
}

// ---------------------------------------------------------------------------
// 86x128 Kron transform + fake quant (dn branch). Dynamic LDS 159104 B.
// 256 threads, 4x8 thread tiles, all-b128 LDS access. L padded to 88 cols
// (zeros) -> garbage output rows 86/87 are exactly zero, land in X padding.
// M1 stored transposed: M1T[j][p], stride 88.
// ---------------------------------------------------------------------------
__global__ __launch_bounds__(256) void tdn_kernel(
    const void* __restrict__ src, int srcIsBf16,
    const float* __restrict__ Lm, const float* __restrict__ Rm,
    const float* __restrict__ diag,
    __hip_bfloat16* __restrict__ outq, float* __restrict__ scales,
    int mulDiag, float qmax, float qlo, float qhi)
{
    extern __shared__ float dsm[];
    float* X  = dsm;              // [88][132] = 11616 (rows 86,87 = padding)
    float* M1 = dsm + 11616;      // M1T [128][88] = 11264
    float* LR = dsm + 22880;      // L [86][88] (padded) or R [128][132] = 16896
    __shared__ float red[256];

    const int tid = threadIdx.x;
    const int row = blockIdx.x;

    // stage X = (src op diag), vectorized 4-wide
    for (int i4 = tid; i4 < IDIM / 4; i4 += 256) {
        const int idx = i4 * 4;
        float4 v;
        if (srcIsBf16) {
            uint2 raw = *(const uint2*)((const unsigned short*)src +
                                        (size_t)row * IDIM + idx);
            v.x = __uint_as_float(raw.x << 16);
            v.y = __uint_as_float(raw.x & 0xffff0000u);
            v.z = __uint_as_float(raw.y << 16);
            v.w = __uint_as_float(raw.y & 0xffff0000u);
        } else {
            v = *(const float4*)((const float*)src + (size_t)row * IDIM + idx);
        }
        float4 d = *(const float4*)(diag + idx);
        if (mulDiag) { v.x *= d.x; v.y *= d.y; v.z *= d.z; v.w *= d.w; }
        else         { v.x /= d.x; v.y /= d.y; v.z /= d.z; v.w /= d.w; }
        *(float4*)&X[(idx >> 7) * 132 + (idx & 127)] = v;
    }
    // L with stride 88, columns 86/87 zeroed
    for (int idx = tid; idx < 86 * 88; idx += 256) {
        const int r = idx / 88, c = idx - r * 88;
        LR[idx] = (c < 86) ? Lm[r * 86 + c] : 0.f;
    }
    __syncthreads();

    // M1[p][j] = sum_i L[i][p] X[i][j]; p-tiles 22 (88/4), j-tiles 16 (128/8)
    for (int tt = tid; tt < 352; tt += 256) {
        const int pp = (tt >> 4) << 2;     // 0..84
        const int jb = (tt & 15) << 3;     // 0..120
        float acc[4][8] = {};
#pragma unroll 2
        for (int i = 0; i < 86; ++i) {
            float4 a  = *(const float4*)&LR[i * 88 + pp];
            float4 b0 = *(const float4*)&X[i * 132 + jb];
            float4 b1 = *(const float4*)&X[i * 132 + jb + 4];
            acc[0][0] += a.x * b0.x; acc[0][1] += a.x * b0.y; acc[0][2] += a.x * b0.z; acc[0][3] += a.x * b0.w;
            acc[0][4] += a.x * b1.x; acc[0][5] += a.x * b1.y; acc[0][6] += a.x * b1.z; acc[0][7] += a.x * b1.w;
            acc[1][0] += a.y * b0.x; acc[1][1] += a.y * b0.y; acc[1][2] += a.y * b0.z; acc[1][3] += a.y * b0.w;
            acc[1][4] += a.y * b1.x; acc[1][5] += a.y * b1.y; acc[1][6] += a.y * b1.z; acc[1][7] += a.y * b1.w;
            acc[2][0] += a.z * b0.x; acc[2][1] += a.z * b0.y; acc[2][2] += a.z * b0.z; acc[2][3] += a.z * b0.w;
            acc[2][4] += a.z * b1.x; acc[2][5] += a.z * b1.y; acc[2][6] += a.z * b1.z; acc[2][7] += a.z * b1.w;
            acc[3][0] += a.w * b0.x; acc[3][1] += a.w * b0.y; acc[3][2] += a.w * b0.z; acc[3][3] += a.w * b0.w;
            acc[3][4] += a.w * b1.x; acc[3][5] += a.w * b1.y; acc[3][6] += a.w * b1.z; acc[3][7] += a.w * b1.w;
        }
#pragma unroll
        for (int jj = 0; jj < 8; ++jj)
            *(float4*)&M1[(jb + jj) * 88 + pp] =
                make_float4(acc[0][jj], acc[1][jj], acc[2][jj], acc[3][jj]);
    }
    __syncthreads();

    // R with stride 132
    for (int i4 = tid; i4 < 4096; i4 += 256) {
        const int idx = i4 * 4;
        *(float4*)&LR[(idx >> 7) * 132 + (idx & 127)] = *(const float4*)(Rm + idx);
    }
    __syncthreads();

    // T[p][q] = sum_j M1T[j][p] R[j][q], into X (dead); track absmax
    float lm = 0.f;
    for (int tt = tid; tt < 352; tt += 256) {
        const int pp = (tt >> 4) << 2;
        const int qb = (tt & 15) << 3;
        float acc[4][8] = {};
#pragma unroll 2
        for (int j = 0; j < 128; ++j) {
            float4 a  = *(const float4*)&M1[j * 88 + pp];
            float4 b0 = *(const float4*)&LR[j * 132 + qb];
            float4 b1 = *(const float4*)&LR[j * 132 + qb + 4];
            acc[0][0] += a.x * b0.x; acc[0][1] += a.x * b0.y; acc[0][2] += a.x * b0.z; acc[0][3] += a.x * b0.w;
            acc[0][4] += a.x * b1.x; acc[0][5] += a.x * b1.y; acc[0][6] += a.x * b1.z; acc[0][7] += a.x * b1.w;
            acc[1][0] += a.y * b0.x; acc[1][1] += a.y * b0.y; acc[1][2] += a.y * b0.z; acc[1][3] += a.y * b0.w;
            acc[1][4] += a.y * b1.x; acc[1][5] += a.y * b1.y; acc[1][6] += a.y * b1.z; acc[1][7] += a.y * b1.w;
            acc[2][0] += a.z * b0.x; acc[2][1] += a.z * b0.y; acc[2][2] += a.z * b0.z; acc[2][3] += a.z * b0.w;
            acc[2][4] += a.z * b1.x; acc[2][5] += a.z * b1.y; acc[2][6] += a.z * b1.z; acc[2][7] += a.z * b1.w;
            acc[3][0] += a.w * b0.x; acc[3][1] += a.w * b0.y; acc[3][2] += a.w * b0.z; acc[3][3] += a.w * b0.w;
            acc[3][4] += a.w * b1.x; acc[3][5] += a.w * b1.y; acc[3][6] += a.w * b1.z; acc[3][7] += a.w * b1.w;
        }
#pragma unroll
        for (int ii = 0; ii < 4; ++ii) {
            *(float4*)&X[(pp + ii) * 132 + qb] =
                make_float4(acc[ii][0], acc[ii][1], acc[ii][2], acc[ii][3]);
            *(float4*)&X[(pp + ii) * 132 + qb + 4] =
                make_float4(acc[ii][4], acc[ii][5], acc[ii][6], acc[ii][7]);
#pragma unroll
            for (int qq = 0; qq < 8; ++qq) lm = fmaxf(lm, fabsf(acc[ii][qq]));
        }
    }
    red[tid] = lm;
    __syncthreads();
    for (int s = 128; s > 0; s >>= 1) {
        if (tid < s) red[tid] = fmaxf(red[tid], red[tid + s]);
        __syncthreads();
    }
    const float sc = fmaxf(red[0] / qmax, 1e-8f);

    for (int i4 = tid; i4 < IDIM / 4; i4 += 256) {
        const int idx = i4 * 4;
        float4 v = *(const float4*)&X[(idx >> 7) * 132 + (idx & 127)];
        float q0 = fminf(fmaxf(rintf(v.x / sc), qlo), qhi);
        float q1 = fminf(fmaxf(rintf(v.y / sc), qlo), qhi);
        float q2 = fminf(fmaxf(rintf(v.z / sc), qlo), qhi);
        float q3 = fminf(fmaxf(rintf(v.w / sc), qlo), qhi);
        unsigned int lo = bf16bits(q0) | (bf16bits(q1) << 16);
        unsigned int hi = bf16bits(q2) | (bf16bits(q3) << 16);
        *(uint2*)(outq + (size_t)row * IDIM + idx) = make_uint2(lo, hi);
    }
    if (tid == 0) scales[row] = sc;
}

// ---------------------------------------------------------------------------
// async global->LDS, 16B per lane. LDS dest is wave-uniform base + lane*16.
// ---------------------------------------------------------------------------
__device__ __forceinline__ void gload16(const __hip_bfloat16* gsrc,
                                        __hip_bfloat16* ldst)
{
    __builtin_amdgcn_global_load_lds(
        (const __attribute__((address_space(1))) unsigned int*)gsrc,
        (__attribute__((address_space(3))) unsigned int*)ldst, 16, 0, 0);
}

// ---------------------------------------------------------------------------
// Tiled bf16 MFMA GEMM, C = A * B^T (both row-major-K). m97-structure:
// 128x128 tile, BK=64, 4 waves (2x2), 4x4 16x16 frags per wave,
// global_load_lds width-16 staging (linear LDS, no VALU round-trip).
// Integer-valued bf16 inputs -> exact integer accumulation in f32.
// DUAL: two B matrices (up/gate) + SwiGLU epilogue -> bf16 h.
// SINGLE: one B + dequant epilogue -> f32 out.
// ---------------------------------------------------------------------------
template <bool DUAL>
__global__ __launch_bounds__(256, 2) void gemm_kernel(
    const __hip_bfloat16* __restrict__ A,
    const __hip_bfloat16* __restrict__ B0,
    const __hip_bfloat16* __restrict__ B1,
    const float* __restrict__ sA,
    const float* __restrict__ sB0,
    const float* __restrict__ sB1,
    int K,
    __hip_bfloat16* __restrict__ outH,
    float* __restrict__ outF,
    int outLd)
{
    constexpr int NT = DUAL ? 3 : 2;
    constexpr int TSZ = 128 * 64;                    // elems per staged tile
    __shared__ __align__(16) __hip_bfloat16 smem[NT * TSZ];

    const int tid = threadIdx.x;
    const int lane = tid & 63;
    const int lane15 = lane & 15;
    const int quad = lane >> 4;
    const int wave = tid >> 6;
    const int wr = wave >> 1;        // wave row (0..1) -> 64-row half
    const int wc = wave & 1;         // wave col (0..1) -> 64-col half
    const int n0 = blockIdx.x * 128;
    const int m0 = blockIdx.y * 128;

    // staging geometry: one gload16 call = 64 lanes * 16B = 8 rows of 64 elems
    const int srow = lane >> 3;          // row within 8-row chunk
    const int scol = (lane & 7) * 8;     // elem col within 64-elem row

    f32x4 acc0[4][4] = {};
    f32x4 acc1[4][4] = {};

    const __hip_bfloat16* gA  = A + (size_t)m0 * K;
    const __hip_bfloat16* gB0 = B0 + (size_t)n0 * K;
    const __hip_bfloat16* gB1 = DUAL ? (B1 + (size_t)n0 * K) : nullptr;

    for (int kk = 0; kk < K; kk += 64) {
        // stage A | B0 | (B1): per wave 4 chunks of 8 rows per tile
#pragma unroll
        for (int c = 0; c < 4; ++c) {
            const int r0 = wave * 32 + c * 8;
            gload16(gA + (size_t)(r0 + srow) * K + kk + scol,
                    smem + r0 * 64);
            gload16(gB0 + (size_t)(r0 + srow) * K + kk + scol,
                    smem + TSZ + r0 * 64);
            if constexpr (DUAL)
                gload16(gB1 + (size_t)(r0 + srow) * K + kk + scol,
                        smem + 2 * TSZ + r0 * 64);
        }
        __syncthreads();   // compiler emits vmcnt(0) drain here (m97 structure)

#pragma unroll
        for (int ks = 0; ks < 2; ++ks) {
            const int kb = ks * 32 + quad * 8;
            bf16x8 af[4];
#pragma unroll
            for (int m = 0; m < 4; ++m)
                af[m] = *(const bf16x8*)(smem +
                         (wr * 64 + m * 16 + lane15) * 64 + kb);
#pragma unroll
            for (int c = 0; c < 4; ++c) {
                bf16x8 b0 = *(const bf16x8*)(smem + TSZ +
                             (wc * 64 + c * 16 + lane15) * 64 + kb);
#pragma unroll
                for (int m = 0; m < 4; ++m)
                    acc0[m][c] = __builtin_amdgcn_mfma_f32_16x16x32_bf16(
                        af[m], b0, acc0[m][c], 0, 0, 0);
                if constexpr (DUAL) {
                    bf16x8 b1 = *(const bf16x8*)(smem + 2 * TSZ +
                                 (wc * 64 + c * 16 + lane15) * 64 + kb);
#pragma unroll
                    for (int m = 0; m < 4; ++m)
                        acc1[m][c] = __builtin_amdgcn_mfma_f32_16x16x32_bf16(
                            af[m], b1, acc1[m][c], 0, 0, 0);
                }
            }
        }
        __syncthreads();
    }

    // Epilogue. Frag D[row=quad*4+r][col=lane15].
#pragma unroll
    for (int m = 0; m < 4; ++m) {
        const int r0 = m0 + wr * 64 + m * 16 + quad * 4;
        float sa[4];
#pragma unroll
        for (int r = 0; r < 4; ++r) sa[r] = sA[r0 + r];
#pragma unroll
        for (int c = 0; c < 4; ++c) {
            const int col = n0 + wc * 64 + c * 16 + lane15;
            if constexpr (DUAL) {
                const float s0 = sB0[col], s1 = sB1[col];
#pragma unroll
                for (int r = 0; r < 4; ++r) {
                    float up = acc0[m][c][r] * (sa[r] * s0);
                    float gt = acc1[m][c][r] * (sa[r] * s1);
                    float hv = up * (gt / (1.f + __expf(-gt)));   // silu(g)*up
                    outH[(size_t)(r0 + r) * outLd + col] = __float2bfloat16(hv);
                }
            } else {
                const float s0 = sB0[col];
#pragma unroll
                for (int r = 0; r < 4; ++r)
                    outF[(size_t)(r0 + r) * outLd + col] =
                        acc0[m][c][r] * (sa[r] * s0);
            }
        }
    }
}

// ---------------------------------------------------------------------------
extern "C" void kernel_launch(void* const* d_in, const int* in_sizes, int n_in,
                              void* d_out, int out_size, void* d_ws, size_t ws_size,
                              hipStream_t stream)
{
    const float* x       = (const float*)d_in[0];
    const float* w_up    = (const float*)d_in[1];
    const float* w_gate  = (const float*)d_in[2];
    const float* w_down  = (const float*)d_in[3];
    const float* up_L    = (const float*)d_in[4];
    const float* up_R    = (const float*)d_in[5];
    const float* up_diag = (const float*)d_in[6];
    const float* dn_L    = (const float*)d_in[7];
    const float* dn_R    = (const float*)d_in[8];
    const float* dn_diag = (const float*)d_in[9];
    float* out = (float*)d_out;

    char* w = (char*)d_ws;
    size_t off = 0;
    auto take = [&](size_t b) { char* p = w + off; off += (b + 255) & ~(size_t)255; return p; };
    __hip_bfloat16* wuq = (__hip_bfloat16*)take((size_t)IDIM * HDIM * 2);
    __hip_bfloat16* wgq = (__hip_bfloat16*)take((size_t)IDIM * HDIM * 2);
    __hip_bfloat16* wdq = (__hip_bfloat16*)take((size_t)HDIM * IDIM * 2);
    __hip_bfloat16* xq  = (__hip_bfloat16*)take((size_t)TOK * HDIM * 2);
    __hip_bfloat16* hq  = (__hip_bfloat16*)take((size_t)TOK * IDIM * 2);
    float* sx = (float*)take(TOK * 4);
    float* su = (float*)take(IDIM * 4);
    float* sg = (float*)take(IDIM * 4);
    float* sh = (float*)take(TOK * 4);
    float* sd = (float*)take(HDIM * 4);
    (void)in_sizes; (void)n_in; (void)out_size; (void)ws_size;

    const size_t tdn_lds = (size_t)(11616 + 11264 + 16896) * sizeof(float); // 159104
    hipFuncSetAttribute(reinterpret_cast<const void*>(&tdn_kernel),
                        hipFuncAttributeMaxDynamicSharedMemorySize, (int)tdn_lds);

    // 1) activation + weight transforms/quant
    t64_kernel<<<TOK,  256, 0, stream>>>(x,      up_L, up_R, up_diag, xq,  sx, 1, 127.f, -128.f, 127.f);
    t64_kernel<<<IDIM, 256, 0, stream>>>(w_up,   up_L, up_R, up_diag, wuq, su, 0, 7.f,   -8.f,   7.f);
    t64_kernel<<<IDIM, 256, 0, stream>>>(w_gate, up_L, up_R, up_diag, wgq, sg, 0, 7.f,   -8.f,   7.f);
    tdn_kernel<<<HDIM, 256, tdn_lds, stream>>>(w_down, 0, dn_L, dn_R, dn_diag, wdq, sd, 0, 7.f, -8.f, 7.f);

    // 2) fused up/gate GEMM + SwiGLU -> h (bf16)  [128x128 tiles]
    gemm_kernel<true><<<dim3(IDIM / 128, TOK / 128), 256, 0, stream>>>(
        xq, wuq, wgq, sx, su, sg, HDIM, hq, nullptr, IDIM);

    // 3) dn transform + quant of h (in place)
    tdn_kernel<<<TOK, 256, tdn_lds, stream>>>(hq, 1, dn_L, dn_R, dn_diag, hq, sh, 1, 127.f, -128.f, 127.f);

    // 4) down GEMM -> f32 output  [128x128 tiles]
    gemm_kernel<false><<<dim3(HDIM / 128, TOK / 128), 256, 0, stream>>>(
        hq, wdq, nullptr, sh, sd, nullptr, IDIM, nullptr, out, HDIM);
}